// Round 21
// baseline (227.499 us; speedup 1.0000x reference)
//
#include <hip/hip_runtime.h>
#include <hip/hip_bf16.h>
#include <stdint.h>

typedef __attribute__((ext_vector_type(8))) short short8;
typedef __attribute__((ext_vector_type(4))) float f32x4;
typedef __attribute__((ext_vector_type(16))) float f32x16;
typedef __attribute__((ext_vector_type(4))) unsigned short us4;

#define SEQ_L 2048
#define NHEADS 16
#define HD 64
#define DMODEL 1024
#define NB 4

__device__ __forceinline__ short f2bf(float f) {
  unsigned int x = __float_as_uint(f);
  x += 0x7fffu + ((x >> 16) & 1u);   // RNE
  return (short)(x >> 16);
}

// packed f32x2 -> bf16x2 (RNE), single HW instruction
__device__ __forceinline__ unsigned cvtpk2(float lo, float hi) {
  unsigned r;
  asm("v_cvt_pk_bf16_f32 %0, %1, %2" : "=v"(r) : "v"(lo), "v"(hi));
  return r;
}

__device__ __forceinline__ float fast_exp2(float x) {
#if __has_builtin(__builtin_amdgcn_exp2f)
  return __builtin_amdgcn_exp2f(x);
#else
  return exp2f(x);
#endif
}

__device__ __forceinline__ void gload16(const void* g, void* l) {
  __builtin_amdgcn_global_load_lds(
      (const __attribute__((address_space(1))) unsigned char*)g,
      (__attribute__((address_space(3))) unsigned char*)l, 16, 0, 0);
}

// ---------------- fp32 -> bf16 conversion (single launch, 6 tensors) --------
__device__ __forceinline__ void conv4(const float* __restrict__ src,
                                      short* __restrict__ dst, int i) {
  float4 f = *reinterpret_cast<const float4*>(src + i);
  us4 o;
  o[0] = (unsigned short)f2bf(f.x);
  o[1] = (unsigned short)f2bf(f.y);
  o[2] = (unsigned short)f2bf(f.z);
  o[3] = (unsigned short)f2bf(f.w);
  *reinterpret_cast<us4*>(dst + i) = o;
}

__global__ void conv6_kernel(const float* __restrict__ s0, short* __restrict__ d0,
                             const float* __restrict__ s1, short* __restrict__ d1,
                             const float* __restrict__ s2, short* __restrict__ d2,
                             const float* __restrict__ s3, short* __restrict__ d3,
                             const float* __restrict__ s4, short* __restrict__ d4,
                             const float* __restrict__ s5, short* __restrict__ d5,
                             int n_big, int n_small) {
  int i = (blockIdx.x * 256 + threadIdx.x) * 4;
  const int y = blockIdx.y;
  const float* s; short* d; int n;
  switch (y) {
    case 0: s = s0; d = d0; n = n_big; break;
    case 1: s = s1; d = d1; n = n_big; break;
    case 2: s = s2; d = d2; n = n_small; break;
    case 3: s = s3; d = d3; n = n_small; break;
    case 4: s = s4; d = d4; n = n_small; break;
    default: s = s5; d = d5; n = n_small; break;
  }
  if (i >= n) return;
  conv4(s, d, i);
}

// ------- fused QKV projection GEMM: z selects {x->q, y->k, y->v} ------------
__global__ void gemm_qkv(const short* __restrict__ xb, const short* __restrict__ yb,
                         const short* __restrict__ Wbase,
                         const float* __restrict__ bq, const float* __restrict__ bk,
                         const float* __restrict__ bv,
                         short* __restrict__ Obase, float qscale) {
  const int z = blockIdx.z;
  const short* A = (z == 0) ? xb : yb;
  const short* W = Wbase + (size_t)z * DMODEL * DMODEL;
  const float* bias = (z == 0) ? bq : ((z == 1) ? bk : bv);
  short* O = Obase + (size_t)z * NB * SEQ_L * DMODEL;
  const float oscale = (z == 0) ? qscale : 1.0f;
  const int K = DMODEL;

  const int tid = threadIdx.x;
  const int w = tid >> 6, l = tid & 63;
  const int tm = blockIdx.x * 128;
  const int tn = blockIdx.y * 128;
  const int wm = (w >> 1) * 64, wn = (w & 1) * 64;
  __shared__ short As[2][128 * 32];
  __shared__ short Bs[2][128 * 32];

  const int srow = w * 32 + (l >> 2);
  const int scol = (l & 3) * 8;
  const short* pa0 = A + (size_t)(tm + srow) * K + scol;
  const short* pa1 = pa0 + (size_t)16 * K;
  const short* pb0 = W + (size_t)(tn + srow) * K + scol;
  const short* pb1 = pb0 + (size_t)16 * K;
  const int ldst = w * 1024 + l * 8;

  gload16(pa0, &As[0][ldst]);
  gload16(pa1, &As[0][ldst + 512]);
  gload16(pb0, &Bs[0][ldst]);
  gload16(pb1, &Bs[0][ldst + 512]);

  f32x4 acc[4][4];
#pragma unroll
  for (int i = 0; i < 4; ++i)
#pragma unroll
    for (int j = 0; j < 4; ++j) acc[i][j] = (f32x4){0.f, 0.f, 0.f, 0.f};

  const int lr = l >> 4, lc = l & 15;
  const int nt = K / 32;
  int cur = 0;
  __syncthreads();
  for (int t = 0; t < nt; ++t) {
    if (t + 1 < nt) {
      int ko = (t + 1) * 32;
      gload16(pa0 + ko, &As[cur ^ 1][ldst]);
      gload16(pa1 + ko, &As[cur ^ 1][ldst + 512]);
      gload16(pb0 + ko, &Bs[cur ^ 1][ldst]);
      gload16(pb1 + ko, &Bs[cur ^ 1][ldst + 512]);
    }
    short8 af[4], bfv[4];
#pragma unroll
    for (int i = 0; i < 4; ++i)
      af[i] = *reinterpret_cast<const short8*>(
          &As[cur][(wm + i * 16 + lc) * 32 + lr * 8]);
#pragma unroll
    for (int j = 0; j < 4; ++j)
      bfv[j] = *reinterpret_cast<const short8*>(
          &Bs[cur][(wn + j * 16 + lc) * 32 + lr * 8]);
#pragma unroll
    for (int i = 0; i < 4; ++i)
#pragma unroll
      for (int j = 0; j < 4; ++j)
        acc[i][j] =
            __builtin_amdgcn_mfma_f32_16x16x32_bf16(af[i], bfv[j], acc[i][j], 0, 0, 0);
    __syncthreads();
    cur ^= 1;
  }

#pragma unroll
  for (int j = 0; j < 4; ++j) {
    int col = tn + wn + j * 16 + lc;
    float bv2 = bias[col];
    int h = col >> 6, d = col & 63;
#pragma unroll
    for (int i = 0; i < 4; ++i)
#pragma unroll
      for (int r = 0; r < 4; ++r) {
        int row = tm + wm + i * 16 + lr * 4 + r;
        int b = row >> 11, pos = row & 2047;
        float vv = (acc[i][j][r] + bv2) * oscale;
        O[(((size_t)(b * NHEADS + h) * SEQ_L + pos) << 6) + d] = f2bf(vv);
      }
  }
}

// ---------------- output projection GEMM (fp32 out + bias) ------------------
__global__ void gemm_out(const short* __restrict__ A, const short* __restrict__ W,
                         const float* __restrict__ bias, float* __restrict__ O,
                         int K) {
  const int tid = threadIdx.x;
  const int w = tid >> 6, l = tid & 63;
  const int tm = blockIdx.x * 128;
  const int tn = blockIdx.y * 128;
  const int wm = (w >> 1) * 64, wn = (w & 1) * 64;
  __shared__ short As[2][128 * 32];
  __shared__ short Bs[2][128 * 32];

  const int srow = w * 32 + (l >> 2);
  const int scol = (l & 3) * 8;
  const short* pa0 = A + (size_t)(tm + srow) * K + scol;
  const short* pa1 = pa0 + (size_t)16 * K;
  const short* pb0 = W + (size_t)(tn + srow) * K + scol;
  const short* pb1 = pb0 + (size_t)16 * K;
  const int ldst = w * 1024 + l * 8;

  gload16(pa0, &As[0][ldst]);
  gload16(pa1, &As[0][ldst + 512]);
  gload16(pb0, &Bs[0][ldst]);
  gload16(pb1, &Bs[0][ldst + 512]);

  f32x4 acc[4][4];
#pragma unroll
  for (int i = 0; i < 4; ++i)
#pragma unroll
    for (int j = 0; j < 4; ++j) acc[i][j] = (f32x4){0.f, 0.f, 0.f, 0.f};

  const int lr = l >> 4, lc = l & 15;
  const int nt = K / 32;
  int cur = 0;
  __syncthreads();
  for (int t = 0; t < nt; ++t) {
    if (t + 1 < nt) {
      int ko = (t + 1) * 32;
      gload16(pa0 + ko, &As[cur ^ 1][ldst]);
      gload16(pa1 + ko, &As[cur ^ 1][ldst + 512]);
      gload16(pb0 + ko, &Bs[cur ^ 1][ldst]);
      gload16(pb1 + ko, &Bs[cur ^ 1][ldst + 512]);
    }
    short8 af[4], bfv[4];
#pragma unroll
    for (int i = 0; i < 4; ++i)
      af[i] = *reinterpret_cast<const short8*>(
          &As[cur][(wm + i * 16 + lc) * 32 + lr * 8]);
#pragma unroll
    for (int j = 0; j < 4; ++j)
      bfv[j] = *reinterpret_cast<const short8*>(
          &Bs[cur][(wn + j * 16 + lc) * 32 + lr * 8]);
#pragma unroll
    for (int i = 0; i < 4; ++i)
#pragma unroll
      for (int j = 0; j < 4; ++j)
        acc[i][j] =
            __builtin_amdgcn_mfma_f32_16x16x32_bf16(af[i], bfv[j], acc[i][j], 0, 0, 0);
    __syncthreads();
    cur ^= 1;
  }

#pragma unroll
  for (int j = 0; j < 4; ++j) {
    int col = tn + wn + j * 16 + lc;
    float bv = bias[col];
#pragma unroll
    for (int i = 0; i < 4; ++i)
#pragma unroll
      for (int r = 0; r < 4; ++r) {
        int row = tm + wm + i * 16 + lr * 4 + r;
        O[(size_t)row * DMODEL + col] = acc[i][j][r] + bv;
      }
  }
}

// ---------------- flash attention (r17 verbatim — last passing) -------------
// QK^T via mfma_f32_32x32x16 (A=Q,B=K; layouts HW-verified r17), fixed-max
// softmax P=exp2(S+mbadj) with mbadj = mask ? -8 : -inf, P through LDS,
// PV via 16x16 MFMAs + ones-MFMA row-sum. K reg-staged; single-buffer KT/VT.
// BANNED (failed on HW): kf-merge, lazy-max, mask-through-MFMA-C-init,
// in-register-P / swapped-QK family (r18-r20: persistent ~8.4 absmax).
__global__ __launch_bounds__(256, 2) void attn_fwd(
    const short* __restrict__ Qh, const short* __restrict__ Kh,
    const short* __restrict__ Vh, const int* __restrict__ mask,
    short* __restrict__ O) {
  const int tid = threadIdx.x;
  const int w = tid >> 6, l = tid & 63;
  const int bid = blockIdx.x;
  const int bh = (bid & 7) | ((bid >> 7) << 3);  // bid%8 == bh%8 -> XCD-stable
  const int qt = (bid >> 3) & 15;
  const int b = bh >> 4, h = bh & 15;
  const short* q = Qh + (size_t)bh * SEQ_L * HD;
  const short* kg = Kh + (size_t)bh * SEQ_L * HD;
  const short* v = Vh + (size_t)bh * SEQ_L * HD;
  const int* mrow = mask + b * SEQ_L;
  const int qbase = qt * 128;

  __shared__ short QP[128 * 64];   // Q staging, then P tile (per-wave regions)
  __shared__ short KT[64 * 64];    // K, single buffer, swizzled
  __shared__ short VT[64 * 64];    // V^T : [d][k], single buffer, swizzled

  auto sw = [](int row, int e) { return row * 64 + (e ^ ((row & 7) << 3)); };

  // stage Q via global_load_lds: linear dest, inverse-swizzled source
#pragma unroll
  for (int qi = 0; qi < 4; ++qi) {
    int c = w * 4 + qi;
    int row = c * 8 + (l >> 3);
    int ss = (l & 7) ^ (l >> 3);
    gload16(q + (size_t)(qbase + row) * HD + ss * 8, &QP[c * 512 + l * 8]);
  }

  const int lr = l >> 4, lc = l & 15;
  const int l31 = l & 31, lhi = l >> 5;   // 32x32 frag coords

  // K reg-staging: wave w owns rows w*16 .. w*16+15
  short8 ka, kb2, va, vb;
  const int krow0 = w * 16 + (l >> 3);
  const int ke0 = ((l & 7) ^ (l >> 3)) * 8;  // swizzled block (rows +8 share it)
  auto loadK = [&](int kbase) {
    const short* kp = kg + (size_t)(kbase + krow0) * HD + (l & 7) * 8;
    ka = *reinterpret_cast<const short8*>(kp);
    kb2 = *reinterpret_cast<const short8*>(kp + (size_t)8 * HD);
  };
  auto writeK = [&]() {
    *reinterpret_cast<short8*>(&KT[krow0 * 64 + ke0]) = ka;
    *reinterpret_cast<short8*>(&KT[(krow0 + 8) * 64 + ke0]) = kb2;
  };
  auto loadV = [&](int kbase) {
    const short* vp = v + (size_t)(kbase + l) * HD + w * 16;
    va = *reinterpret_cast<const short8*>(vp);
    vb = *reinterpret_cast<const short8*>(vp + 8);
  };
  auto writeV = [&]() {
#pragma unroll
    for (int e = 0; e < 8; ++e) {
      VT[sw(w * 16 + e, l)] = va[e];
      VT[sw(w * 16 + 8 + e, l)] = vb[e];
    }
  };

  // ones B-fragment for the row-sum MFMA
  short8 ones;
#pragma unroll
  for (int e = 0; e < 8; ++e) ones[e] = (short)0x3F80;

  // prologue: chunk 0
  loadK(0);
  loadV(0);
  writeK();
  writeV();
  __syncthreads();   // drains Q gloads; K/V ds_writes visible

  // A-frags for 32x32x16 QK: q rows w*32 + (l&31), k = s16*16 + (l>>5)*8
  short8 qf4[4];
#pragma unroll
  for (int s16 = 0; s16 < 4; ++s16)
    qf4[s16] = *reinterpret_cast<const short8*>(
        &QP[sw(w * 32 + l31, s16 * 16 + lhi * 8)]);

  f32x4 acc_o[2][4], acc_sum[2];
#pragma unroll
  for (int i = 0; i < 2; ++i) {
    acc_sum[i] = (f32x4){0.f, 0.f, 0.f, 0.f};
#pragma unroll
    for (int j = 0; j < 4; ++j) acc_o[i][j] = (f32x4){0.f, 0.f, 0.f, 0.f};
  }

  // QK^T one 32x32 block (kk = blk*32 .. +31), K=64 contraction in 4 steps
  auto qk_blk = [&](int blk, f32x16& acc) {
#pragma unroll
    for (int e = 0; e < 16; ++e) acc[e] = 0.f;
    __builtin_amdgcn_s_setprio(1);
#pragma unroll
    for (int s16 = 0; s16 < 4; ++s16) {
      short8 kfr = *reinterpret_cast<const short8*>(
          &KT[sw(blk * 32 + l31, s16 * 16 + lhi * 8)]);
      acc = __builtin_amdgcn_mfma_f32_32x32x16_bf16(qf4[s16], kfr, acc, 0, 0, 0);
    }
    __builtin_amdgcn_s_setprio(0);
  };

  // fixed-max softmax for one block: P = exp2(S + mbadj); 32x32 C layout
  auto softmax_blk = [&](int blk, f32x16& acc, float mbadj) {
    const int col = blk * 32 + l31;
#pragma unroll
    for (int t = 0; t < 8; ++t) {
      const int reg = 2 * t;
      float p0 = fast_exp2(acc[reg] + mbadj);
      float p1 = fast_exp2(acc[reg + 1] + mbadj);
      unsigned u = cvtpk2(p0, p1);
      const int row = w * 32 + (reg & 3) + 8 * (reg >> 2) + 4 * lhi;
      QP[sw(row, col)] = (short)u;
      QP[sw(row + 1, col)] = (short)(u >> 16);
    }
  };

  const int NT = SEQ_L / 64;
  for (int ic = 0; ic < NT; ++ic) {
    const int kb = ic * 64;
    const bool pf = (ic + 1 < NT);
    if (pf) {            // issue next-chunk loads; hidden under whole iter
      loadV(kb + 64);
      loadK(kb + 64);
    }

    float mb2[2];
#pragma unroll
    for (int blk = 0; blk < 2; ++blk)
      mb2[blk] = mrow[kb + blk * 32 + l31] ? -8.0f : -__builtin_inff();

    f32x16 sB0;
    qk_blk(0, sB0);
    softmax_blk(0, sB0, mb2[0]);
    f32x16 sB1;
    qk_blk(1, sB1);                 // last KT reads of this iteration
    __syncthreads();                // bar1: all waves done reading KT
    if (pf) writeK();               // next K -> KT (ds_write, no vmcnt drain)
    softmax_blk(1, sB1, mb2[1]);

    // O += P V ; l += P . 1   (P region is wave-private; PV stays 16x16)
    __builtin_amdgcn_s_setprio(1);
#pragma unroll
    for (int s = 0; s < 2; ++s) {
      short8 vf[4];
#pragma unroll
      for (int j = 0; j < 4; ++j)
        vf[j] = *reinterpret_cast<const short8*>(
            &VT[sw(j * 16 + lc, s * 32 + lr * 8)]);
#pragma unroll
      for (int i = 0; i < 2; ++i) {
        short8 pf2 = *reinterpret_cast<const short8*>(
            &QP[sw(w * 32 + i * 16 + lc, s * 32 + lr * 8)]);
#pragma unroll
        for (int j = 0; j < 4; ++j)
          acc_o[i][j] =
              __builtin_amdgcn_mfma_f32_16x16x32_bf16(pf2, vf[j], acc_o[i][j], 0, 0, 0);
        acc_sum[i] =
            __builtin_amdgcn_mfma_f32_16x16x32_bf16(pf2, ones, acc_sum[i], 0, 0, 0);
      }
    }
    __builtin_amdgcn_s_setprio(0);

    __syncthreads();                // bar2: VT reads done; KT writes visible
    if (pf) writeV();               // next V -> VT (visible by next bar1)
  }

  // epilogue: O / l, bf16, [B, Q, D] layout for the output projection
#pragma unroll
  for (int i = 0; i < 2; ++i)
#pragma unroll
    for (int j = 0; j < 4; ++j)
#pragma unroll
      for (int r = 0; r < 4; ++r) {
        int row = qbase + w * 32 + i * 16 + lr * 4 + r;
        int d = j * 16 + lc;
        float ov = acc_o[i][j][r] / acc_sum[i][r];
        O[(size_t)(b * SEQ_L + row) * DMODEL + h * HD + d] = f2bf(ov);
      }
}

// ---------------- launch ----------------------------------------------------
extern "C" void kernel_launch(void* const* d_in, const int* in_sizes, int n_in,
                              void* d_out, int out_size, void* d_ws, size_t ws_size,
                              hipStream_t stream) {
  (void)in_sizes; (void)n_in; (void)out_size; (void)ws_size;
  const float* x  = (const float*)d_in[0];
  const float* y  = (const float*)d_in[1];
  const int* mask = (const int*)d_in[2];
  const float* Wq = (const float*)d_in[3];
  const float* bq = (const float*)d_in[4];
  const float* Wk = (const float*)d_in[5];
  const float* bk = (const float*)d_in[6];
  const float* Wv = (const float*)d_in[7];
  const float* bv = (const float*)d_in[8];
  const float* Wo = (const float*)d_in[9];
  const float* bo = (const float*)d_in[10];
  float* out = (float*)d_out;

  const size_t MQ = (size_t)NB * SEQ_L;
  const size_t TOK = MQ * DMODEL;
  const size_t TOKB = TOK * 2;
  const size_t WB = (size_t)DMODEL * DMODEL * 2;

  char* ws = (char*)d_ws;
  short* xb  = (short*)ws;            ws += TOKB;
  short* yb  = (short*)ws;            ws += TOKB;
  short* wqb = (short*)ws;            ws += WB;   // wqb, wkb, wvb contiguous
  short* wkb = (short*)ws;            ws += WB;
  short* wvb = (short*)ws;            ws += WB;
  short* wob = (short*)ws;            ws += WB;
  short* qh  = (short*)ws;            ws += TOKB; // qh, kh, vh contiguous
  short* kh  = (short*)ws;            ws += TOKB;
  short* vh  = (short*)ws;            ws += TOKB;
  short* attnb = xb;                  // alias: xb dead after q projection
  (void)wkb; (void)wvb;

  const int W2 = DMODEL * DMODEL;
  conv6_kernel<<<dim3((unsigned)(TOK / 1024), 6), 256, 0, stream>>>(
      x, xb, y, yb, Wq, wqb, Wk, wkb, Wv, wvb, Wo, wob, (int)TOK, W2);

  const float qscale = 0.125f * 1.44269504089f;  // 1/sqrt(64) * log2(e)
  gemm_qkv<<<dim3(64, 8, 3), 256, 0, stream>>>(
      xb, yb, wqb, bq, bk, bv, qh, qscale);

  attn_fwd<<<dim3(1024), 256, 0, stream>>>(qh, kh, vh, mask, attnb);

  gemm_out<<<dim3(64, 8), 256, 0, stream>>>(attnb, wob, bo, out, DMODEL);
}